// Round 16
// baseline (608.017 us; speedup 1.0000x reference)
//
#include <hip/hip_runtime.h>
#include <stdint.h>

#define BATCH 8
#define C 128
#define TPB 256
#define GEMM_BLOCKS 1024  // persistent; 4 blocks/CU offered (32KB LDS each)
#define TILE_R 256        // rows per tile-job
#define HGRID 2048

// order-preserving float -> uint key (monotone: a<b  <=>  key(a)<key(b))
__device__ __forceinline__ unsigned f2key(float f){
  unsigned b = __float_as_uint(f);
  return (b & 0x80000000u) ? ~b : (b | 0x80000000u);
}

// ---------------------------------------------------------------------------
// Outer-product GEMM, r15 body (120 VGPR, conflict-clean, zero main-loop
// barriers) with W1 SPLIT BY COLUMN HALF to lift occupancy:
// r9/r11/r15 all plateau at ~445us with 2 waves/SIMD (19-21% occupancy);
// r15 showed VALU-issue is not the wall (busy 48->61% at equal time), so the
// wall is stall exposure at 2 waves/SIMD. r15's 66KB LDS (full W1) capped
// blocks at 2/CU. Split: block = 4 waves x (64x64) = 256 rows x 64 cols job;
// sW1t = 32KB (one col-half, transposed + XOR-granule swizzle, staged once
// per persistent block since grid stride 1024 preserves half parity).
// 4 blocks/CU offered; VGPR 120 -> 3-4 waves/SIMD (1-wave granularity).
// Pred under col-split: per-half f64 butterfly partial -> predpart[half][row]
// (global, no atomics); k_pred does (float)(pp0+pp1+b2) = bit-identical
// order to r15's sPred[tid]+sPred[128+tid]+b2d. Deterministic.
// A: direct global reads, natural layout (L1-line reuse over 4 k-groups).
// B: 2 LDS b128 per k per wave, conflict-free (granule = (k>>2)^((c>>3)&7)).
// FMA chains (h and pred) operand/order-identical to rounds 1-15.
// r13 lesson: TPB=512 hard-caps VGPR at 128 - this body must stay TPB=256.
// ---------------------------------------------------------------------------
__global__ __launch_bounds__(TPB, 1) void k_gemm(
    const float* __restrict__ fea, const float* __restrict__ W1,
    const float* __restrict__ b1, const float* __restrict__ W2,
    const float* __restrict__ b2, float* __restrict__ out,
    double* __restrict__ predpart, int N)
{
  __shared__ float sW1t[64 * C];   // 32KB: W1[k][half*64+cl] at [cl][swz(k)]

  const int tid  = threadIdx.x;
  const int lane = tid & 63;
  const int wid  = tid >> 6;              // 0..3 (wave = 64x64 tile)
  const int half = blockIdx.x & 1;        // col-half, fixed per block
  const int clb  = (lane & 7) * 8;        // local col base 0..56
  const int coloff = half * 64 + clb;     // global col base
  const int rowloc = wid * 64 + (lane >> 3) * 8;   // in-tile row base 0..248
  const int lmask  = lane & 7;

  // ---- stage this block's W1 col-half, transposed + granule-swizzled ----
  for (int idx = tid; idx < 64 * C; idx += TPB) {
    int k = idx >> 6, cl = idx & 63;      // coalesced read of W1[k][.]
    sW1t[cl * C + (((k >> 2) ^ ((cl >> 3) & 7)) << 2) + (k & 3)] =
        W1[k * C + half * 64 + cl];
  }
  float b1v[8];
  #pragma unroll
  for (int i = 0; i < 8; ++i) b1v[i] = b1[coloff + i];
  __syncthreads();

  const float* bcol = &sW1t[clb * C];
  const int nJobs = (N / TILE_R) * 2;     // 6250 (tile, half) jobs

  for (int job = blockIdx.x; job < nJobs; job += GEMM_BLOCKS) {
    const int tile = job >> 1;            // (job & 1) == half, invariant
    const size_t trow = (size_t)tile * TILE_R;
    const float* abase = fea + (trow + rowloc) * C;

    float4 Aa[8], Ab[8];
    #pragma unroll
    for (int j = 0; j < 8; ++j) Aa[j] = *(const float4*)(abase + j * C);

    float acc[8][8];
    #pragma unroll
    for (int j = 0; j < 8; ++j)
      #pragma unroll
      for (int i = 0; i < 8; ++i) acc[j][i] = b1v[i];

    #pragma unroll 1
    for (int kg = 0; kg < 32; kg += 2) {
      // ---- half 1: compute group kg (Aa), prefetch kg+1 -> Ab ----
      #pragma unroll
      for (int j = 0; j < 8; ++j)
        Ab[j] = *(const float4*)(abase + j * C + (kg + 1) * 4);
      {
        const int goff = ((kg ^ lmask) << 2);
        float4 Bv[8];
        #pragma unroll
        for (int i = 0; i < 8; ++i)
          Bv[i] = *(const float4*)(bcol + i * C + goff);
        #pragma unroll
        for (int j = 0; j < 8; ++j) {   // k ascending per (j,i) chain
          #pragma unroll
          for (int i = 0; i < 8; ++i) acc[j][i] = fmaf(Aa[j].x, Bv[i].x, acc[j][i]);
          #pragma unroll
          for (int i = 0; i < 8; ++i) acc[j][i] = fmaf(Aa[j].y, Bv[i].y, acc[j][i]);
          #pragma unroll
          for (int i = 0; i < 8; ++i) acc[j][i] = fmaf(Aa[j].z, Bv[i].z, acc[j][i]);
          #pragma unroll
          for (int i = 0; i < 8; ++i) acc[j][i] = fmaf(Aa[j].w, Bv[i].w, acc[j][i]);
        }
      }
      // ---- half 2: compute group kg+1 (Ab), prefetch kg+2 -> Aa ----
      if (kg + 2 < 32) {
        #pragma unroll
        for (int j = 0; j < 8; ++j)
          Aa[j] = *(const float4*)(abase + j * C + (kg + 2) * 4);
      }
      {
        const int goff = (((kg + 1) ^ lmask) << 2);
        float4 Bv[8];
        #pragma unroll
        for (int i = 0; i < 8; ++i)
          Bv[i] = *(const float4*)(bcol + i * C + goff);
        #pragma unroll
        for (int j = 0; j < 8; ++j) {
          #pragma unroll
          for (int i = 0; i < 8; ++i) acc[j][i] = fmaf(Ab[j].x, Bv[i].x, acc[j][i]);
          #pragma unroll
          for (int i = 0; i < 8; ++i) acc[j][i] = fmaf(Ab[j].y, Bv[i].y, acc[j][i]);
          #pragma unroll
          for (int i = 0; i < 8; ++i) acc[j][i] = fmaf(Ab[j].z, Bv[i].z, acc[j][i]);
          #pragma unroll
          for (int i = 0; i < 8; ++i) acc[j][i] = fmaf(Ab[j].w, Bv[i].w, acc[j][i]);
        }
      }
    }

    // ---- epilogue: relu + store h (this half), f64 partial pred ----
    float w2f[8];
    #pragma unroll
    for (int i = 0; i < 8; ++i) w2f[i] = W2[coloff + i];
    double pdv[8];
    #pragma unroll
    for (int j = 0; j < 8; ++j) {
      float hv[8];
      #pragma unroll
      for (int i = 0; i < 8; ++i) hv[i] = fmaxf(acc[j][i], 0.f);
      const size_t row = trow + rowloc + j;
      *(float4*)(out + row * C + coloff)     = make_float4(hv[0], hv[1], hv[2], hv[3]);
      *(float4*)(out + row * C + coloff + 4) = make_float4(hv[4], hv[5], hv[6], hv[7]);
      double pd = 0.0;
      #pragma unroll
      for (int i = 0; i < 8; ++i) pd += (double)hv[i] * (double)w2f[i];
      pdv[j] = pd;
    }
    #pragma unroll
    for (int j = 0; j < 8; ++j) {   // butterfly over the 8-lane col group
      double pd = pdv[j];
      pd += __shfl_xor(pd, 1, 64);
      pd += __shfl_xor(pd, 2, 64);
      pd += __shfl_xor(pd, 4, 64);
      pdv[j] = pd;
    }
    if ((lane & 7) == 0) {
      #pragma unroll
      for (int j = 0; j < 8; ++j)
        predpart[(size_t)half * N + trow + rowloc + j] = pdv[j];
    }
  }
}

// pred = (float)(pp_half0 + pp_half1 + b2)  -- bit-identical order to r15.
__global__ __launch_bounds__(256) void k_pred(
    const double* __restrict__ pp, const float* __restrict__ b2,
    const int* __restrict__ vox, float* __restrict__ pred,
    unsigned* __restrict__ segkey, int N)
{
  int i = blockIdx.x * 256 + threadIdx.x;
  if (i >= N) return;
  const float pv = (float)(pp[i] + pp[(size_t)N + i] + (double)b2[0]);
  pred[i] = pv;
  atomicMax(&segkey[vox[i]], f2key(pv));
}

// ---------------------------------------------------------------------------
// Pass A: valkey + per-row histogram of byte1 (vk>>24), LDS-accumulated.
// ---------------------------------------------------------------------------
__global__ __launch_bounds__(256) void k_histA(
    const float* __restrict__ pred, const int* __restrict__ vox,
    const unsigned* __restrict__ segkey, unsigned* __restrict__ valkey,
    unsigned* __restrict__ histA, int N, int M)
{
  __shared__ unsigned lh[BATCH * 256];
  for (int b = threadIdx.x; b < BATCH * 256; b += 256) lh[b] = 0;
  __syncthreads();
  const int stride = gridDim.x * 256;
  for (int i = blockIdx.x * 256 + threadIdx.x; i < N; i += stride) {
    unsigned kk = f2key(pred[i]);
    unsigned vk = (kk == segkey[vox[i]]) ? 0xFFFFFFFFu : kk;
    valkey[i] = vk;
    atomicAdd(&lh[(i / M) * 256 + (vk >> 24)], 1u);
  }
  __syncthreads();
  for (int b = threadIdx.x; b < BATCH * 256; b += 256)
    if (lh[b]) atomicAdd(&histA[b], lh[b]);
}

// Pass B: byte2 among elements whose byte1 matches the selected bin.
__global__ __launch_bounds__(256) void k_histB(
    const unsigned* __restrict__ valkey, const unsigned* __restrict__ sel,
    unsigned* __restrict__ histB, int N, int M)
{
  __shared__ unsigned lh[BATCH * 256];
  for (int b = threadIdx.x; b < BATCH * 256; b += 256) lh[b] = 0;
  __syncthreads();
  const int stride = gridDim.x * 256;
  for (int i = blockIdx.x * 256 + threadIdx.x; i < N; i += stride) {
    unsigned vk = valkey[i];
    int row = i / M;
    if ((vk >> 24) == sel[row * 4 + 0])
      atomicAdd(&lh[row * 256 + ((vk >> 16) & 255u)], 1u);
  }
  __syncthreads();
  for (int b = threadIdx.x; b < BATCH * 256; b += 256)
    if (lh[b]) atomicAdd(&histB[b], lh[b]);
}

// Pass C: low 16 bits among elements whose top16 matches (few -> global ok).
__global__ __launch_bounds__(256) void k_histC(
    const unsigned* __restrict__ valkey, const unsigned* __restrict__ sel,
    unsigned* __restrict__ histC, int N, int M)
{
  const int stride = gridDim.x * 256;
  for (int i = blockIdx.x * 256 + threadIdx.x; i < N; i += stride) {
    unsigned vk = valkey[i];
    int row = i / M;
    if ((vk >> 16) == sel[row * 4 + 0])
      atomicAdd(&histC[(size_t)row * 65536 + (vk & 0xFFFFu)], 1u);
  }
}

// scans: find smallest bin with cumulative count >= k (k = M - target_num)
__global__ void k_scan256(const unsigned* __restrict__ hist,
                          unsigned* __restrict__ sel,
                          const int* __restrict__ tnum, int M, int pass)
{
  const int row = blockIdx.x;
  __shared__ unsigned h[256];
  h[threadIdx.x] = hist[row * 256 + threadIdx.x];
  __syncthreads();
  if (threadIdx.x == 0) {
    const unsigned k = (unsigned)(M - tnum[0]);
    unsigned cum = (pass == 0) ? 0u : sel[row * 4 + 1];
    unsigned bin = 255;
    for (int i = 0; i < 256; ++i) {
      if (cum + h[i] >= k) { bin = (unsigned)i; break; }
      cum += h[i];
    }
    if (pass == 0) { sel[row * 4 + 0] = bin; }
    else           { sel[row * 4 + 0] = (sel[row * 4 + 0] << 8) | bin; }
    sel[row * 4 + 1] = cum;
  }
}

__global__ void k_scan64k(const unsigned* __restrict__ hist,
                          unsigned* __restrict__ sel,
                          const int* __restrict__ tnum, int M)
{
  const int row = blockIdx.x;
  const int t = threadIdx.x;  // 256
  const unsigned* h = hist + (size_t)row * 65536;
  __shared__ unsigned part[256];
  const uint4* hv = (const uint4*)(h + t * 256);
  unsigned s = 0;
  for (int i = 0; i < 64; ++i) { uint4 v = hv[i]; s += v.x + v.y + v.z + v.w; }
  part[t] = s;
  __syncthreads();
  if (t == 0) {
    const unsigned k = (unsigned)(M - tnum[0]);
    unsigned cum = sel[row * 4 + 1];
    int seg = 255;
    for (int i = 0; i < 256; ++i) {
      if (cum + part[i] >= k) { seg = i; break; }
      cum += part[i];
    }
    unsigned bin = 0;
    for (int i = 0; i < 256; ++i) {
      unsigned c = h[seg * 256 + i];
      if (cum + c >= k) { bin = (unsigned)(seg * 256 + i); break; }
      cum += c;
    }
    sel[row * 4 + 2] = (sel[row * 4 + 0] << 16) | bin;
  }
}

__global__ void k_scatter(const int* __restrict__ tidx, float* __restrict__ kt, int n)
{
  int i = blockIdx.x * blockDim.x + threadIdx.x;
  if (i < n) kt[tidx[i]] = 1.0f;
}

// zero rows that are not kept.  keep = (valkey > thr) | is_target
__global__ __launch_bounds__(256) void k_final(const unsigned* __restrict__ valkey,
    const float* __restrict__ kt, const unsigned* __restrict__ sel,
    float* __restrict__ out, int N, int M)
{
  const int wid = threadIdx.x >> 6;
  const int lane = threadIdx.x & 63;
  const int nw = gridDim.x * 4;
  for (int r = blockIdx.x * 4 + wid; r < N; r += nw) {
    unsigned vk = valkey[r];
    float kv = kt[r];
    unsigned thr = sel[(r / M) * 4 + 2];
    bool keep = (vk > thr) || (kv != 0.0f);
    if (!keep)
      *(float2*)&out[(size_t)r * C + lane * 2] = make_float2(0.f, 0.f);
  }
}

// ---------------------------------------------------------------------------
extern "C" void kernel_launch(void* const* d_in, const int* in_sizes, int n_in,
                              void* d_out, int out_size, void* d_ws, size_t ws_size,
                              hipStream_t stream)
{
  const float* fea = (const float*)d_in[0];
  const float* W1  = (const float*)d_in[1];
  const float* b1  = (const float*)d_in[2];
  const float* W2  = (const float*)d_in[3];
  const float* b2  = (const float*)d_in[4];
  const int* vox   = (const int*)d_in[5];
  const int* tidx  = (const int*)d_in[6];
  const int* tnum  = (const int*)d_in[7];

  const int N = in_sizes[5];      // 800000
  const int M = N / BATCH;        // 100000
  const int nT = in_sizes[6];     // 400000

  float* out  = (float*)d_out;
  float* pred = out + (size_t)N * C;
  float* kt   = pred + N;

  // workspace layout (zeroed region first, then valkey, then predpart)
  char* w = (char*)d_ws;
  unsigned* segkey = (unsigned*)(w);                       // 512KB
  unsigned* histA  = (unsigned*)(w + (512u << 10));        // 8KB
  unsigned* histB  = (unsigned*)(w + (520u << 10));        // 8KB
  unsigned* sel    = (unsigned*)(w + (528u << 10));        // 4KB
  unsigned* histC  = (unsigned*)(w + (532u << 10));        // 2MB
  unsigned* valkey = (unsigned*)(w + (532u << 10) + (2u << 20));          // 3.2MB
  double*  ppart   = (double*)(w + (532u << 10) + (2u << 20) + (size_t)N * 4);  // 12.8MB

  const size_t zbytes = (532u << 10) + (2u << 20);
  hipMemsetAsync(d_ws, 0, zbytes, stream);
  hipMemsetAsync(kt, 0, (size_t)N * sizeof(float), stream);

  k_scatter<<<(nT + 255) / 256, 256, 0, stream>>>(tidx, kt, nT);
  k_gemm<<<GEMM_BLOCKS, TPB, 0, stream>>>(fea, W1, b1, W2, b2,
                                          out, ppart, N);
  k_pred<<<(N + 255) / 256, 256, 0, stream>>>(ppart, b2, vox, pred, segkey, N);
  k_histA<<<HGRID, 256, 0, stream>>>(pred, vox, segkey, valkey, histA, N, M);
  k_scan256<<<BATCH, 256, 0, stream>>>(histA, sel, tnum, M, 0);
  k_histB<<<HGRID, 256, 0, stream>>>(valkey, sel, histB, N, M);
  k_scan256<<<BATCH, 256, 0, stream>>>(histB, sel, tnum, M, 1);
  k_histC<<<HGRID, 256, 0, stream>>>(valkey, sel, histC, N, M);
  k_scan64k<<<BATCH, 256, 0, stream>>>(histC, sel, tnum, M);
  k_final<<<2048, 256, 0, stream>>>(valkey, kt, sel, out, N, M);
}

// Round 17
// 549.503 us; speedup vs baseline: 1.1065x; 1.1065x over previous
//
#include <hip/hip_runtime.h>
#include <stdint.h>

#define BATCH 8
#define C 128
#define TPB 256
#define GEMM_BLOCKS 1024
#define TILE_R 128
#define KC 8
#define NCHUNK (C / KC)   // 16
#define HGRID 2048

// order-preserving float -> uint key (monotone: a<b  <=>  key(a)<key(b))
__device__ __forceinline__ unsigned f2key(float f){
  unsigned b = __float_as_uint(f);
  return (b & 0x80000000u) ? ~b : (b | 0x80000000u);
}

// ---------------------------------------------------------------------------
// Outer-product GEMM (round-11 configuration, the session's best: 550.8us).
// 256-thread blocks (4 waves, 2x2), tile 128x128, 8x8 outputs/thread,
// one-k-deep register pipeline. B (W1, 64KB, L2-hot) from global; A (fea)
// in LDS [2][8][128] double-buffered. 124 VGPR, no spill.
// PLATEAU EVIDENCE (r5-r16): eight structural variants -- LDS 8..144KB,
// VGPR 84..256, TPB 256/512, operands LDS vs VMEM, +-pipeline, +-barriers,
// bank-conflict-free swizzles, col-split occupancy boost -- ALL land at
// 443-452us k_gemm. No bandwidth counter near ceiling (LDS 29/69 TB/s,
// HBM 18%); VALUBusy 45-62%; occupancy ~20% invariant. The kernel sits at
// the register-pressure/arithmetic-intensity balance point of f32 vector
// GEMM on this chip at HIP source level.
// Numerics: h chain = b1-init + fmaf k-ascending; pred = f64 dot + butterfly
// (xor 1/2/4) + two-half LDS combine -- operand/order-identical to all
// passing rounds (absmax 0.0078125, 16/16 passes). DO NOT ALTER.
// Known traps: TPB=512 hard-caps 128 VGPR (r13); launch_bounds (512,4)/
// (512,2)/(256,3) force spill (r3/r4/r6); packed v_pk_fma regresses (r12).
// ---------------------------------------------------------------------------
__global__ __launch_bounds__(TPB, 1) void k_gemm(
    const float* __restrict__ fea, const float* __restrict__ W1,
    const float* __restrict__ b1, const float* __restrict__ W2,
    const float* __restrict__ b2, const int* __restrict__ vox,
    float* __restrict__ out, float* __restrict__ pred,
    unsigned* __restrict__ segkey, int N)
{
  __shared__ float sA[2][KC][TILE_R];   // 8KB, transposed fea tile, dbuf

  const int tid  = threadIdx.x;
  const int lane = tid & 63;
  const int wid  = tid >> 6;              // 0..3
  const int wr   = wid >> 1;              // 0..1 row-group
  const int wc   = wid & 1;               // 0..1 col-group
  const int rowoff = wr * 64 + (lane >> 3) * 8;   // in-tile row base (0..120)
  const int coloff = wc * 64 + (lane & 7) * 8;    // col base (0..120)

  float b1v[8];
  #pragma unroll
  for (int i = 0; i < 8; ++i) b1v[i] = b1[coloff + i];
  const double b2d = (double)b2[0];

  const int nTiles = N / TILE_R;          // 6250
  const int srow = tid >> 1;              // staging: row in tile (0..127)
  const int skq  = tid & 1;               // which float4 of the 8-k chunk

  for (int tile = blockIdx.x; tile < nTiles; tile += GEMM_BLOCKS) {
    const size_t trow = (size_t)tile * TILE_R;

    // ---- prologue: stage chunk 0 ----
    float4 st = *(const float4*)(fea + (trow + srow) * C + skq * 4);
    {
      float* d = &sA[0][skq * 4][srow];
      d[0] = st.x; d[TILE_R] = st.y; d[2 * TILE_R] = st.z; d[3 * TILE_R] = st.w;
    }
    __syncthreads();

    float acc[8][8];
    #pragma unroll
    for (int j = 0; j < 8; ++j)
      #pragma unroll
      for (int i = 0; i < 8; ++i) acc[j][i] = b1v[i];

    // ---- k-chunk loop: one barrier per chunk; frags pipelined 1 k ahead ----
    #pragma unroll 1
    for (int kb = 0; kb < NCHUNK; ++kb) {
      if (kb + 1 < NCHUNK)   // global prefetch of next fea chunk
        st = *(const float4*)(fea + (trow + srow) * C + (kb + 1) * KC + skq * 4);

      const float* sAc = &sA[kb & 1][0][0];
      const float* wrow = W1 + kb * KC * C;   // L2-hot (64KB total)

      // k=0 fragments
      float4 a0 = *(const float4*)(sAc + rowoff);
      float4 a1 = *(const float4*)(sAc + rowoff + 4);
      float4 bA = *(const float4*)(wrow + coloff);
      float4 bB = *(const float4*)(wrow + coloff + 4);

      #pragma unroll
      for (int k = 0; k < KC; ++k) {
        float4 na0, na1, nbA, nbB;
        if (k + 1 < KC) {   // issue k+1 reads BEFORE k's FMAs
          na0 = *(const float4*)(sAc + (k + 1) * TILE_R + rowoff);
          na1 = *(const float4*)(sAc + (k + 1) * TILE_R + rowoff + 4);
          nbA = *(const float4*)(wrow + (k + 1) * C + coloff);
          nbB = *(const float4*)(wrow + (k + 1) * C + coloff + 4);
        }
        float af[8] = {a0.x, a0.y, a0.z, a0.w, a1.x, a1.y, a1.z, a1.w};
        float bf[8] = {bA.x, bA.y, bA.z, bA.w, bB.x, bB.y, bB.z, bB.w};
        #pragma unroll
        for (int j = 0; j < 8; ++j)
          #pragma unroll
          for (int i = 0; i < 8; ++i)
            acc[j][i] = fmaf(af[j], bf[i], acc[j][i]);
        if (k + 1 < KC) { a0 = na0; a1 = na1; bA = nbA; bB = nbB; }
      }

      if (kb + 1 < NCHUNK) {
        float* d = &sA[(kb + 1) & 1][skq * 4][srow];
        d[0] = st.x; d[TILE_R] = st.y; d[2 * TILE_R] = st.z; d[3 * TILE_R] = st.w;
      }
      __syncthreads();
    }

    // ---- epilogue: relu + store h, f64 pred, segment max ----
    float w2f[8];
    #pragma unroll
    for (int i = 0; i < 8; ++i) w2f[i] = W2[coloff + i];
    double pdv[8];
    #pragma unroll
    for (int j = 0; j < 8; ++j) {
      float hv[8];
      #pragma unroll
      for (int i = 0; i < 8; ++i) hv[i] = fmaxf(acc[j][i], 0.f);
      const size_t row = trow + rowoff + j;
      *(float4*)(out + row * C + coloff)     = make_float4(hv[0], hv[1], hv[2], hv[3]);
      *(float4*)(out + row * C + coloff + 4) = make_float4(hv[4], hv[5], hv[6], hv[7]);
      double pd = 0.0;
      #pragma unroll
      for (int i = 0; i < 8; ++i) pd += (double)hv[i] * (double)w2f[i];
      pdv[j] = pd;
    }
    #pragma unroll
    for (int j = 0; j < 8; ++j) {   // reduce over the 8-lane col group
      double pd = pdv[j];
      pd += __shfl_xor(pd, 1, 64);
      pd += __shfl_xor(pd, 2, 64);
      pd += __shfl_xor(pd, 4, 64);
      pdv[j] = pd;
    }
    double* sPred = (double*)&sA[0][0][0];   // 256 doubles (2KB) overlay
    if ((lane & 7) == 0) {
      #pragma unroll
      for (int j = 0; j < 8; ++j) sPred[wc * TILE_R + rowoff + j] = pdv[j];
    }
    __syncthreads();
    {
      const size_t row = trow + tid;        // tid covers 0..255 >= TILE_R? no:
      if (tid < TILE_R) {                   // TILE_R=128, guard
        const double s = sPred[tid] + sPred[TILE_R + tid] + b2d;
        const float pv = (float)s;
        pred[row] = pv;
        atomicMax(&segkey[vox[row]], f2key(pv));
      }
    }
    __syncthreads();   // sPred consumed before next tile's staging write
  }
}

// ---------------------------------------------------------------------------
// Pass A: valkey + per-row histogram of byte1 (vk>>24), LDS-accumulated.
// ---------------------------------------------------------------------------
__global__ __launch_bounds__(256) void k_histA(
    const float* __restrict__ pred, const int* __restrict__ vox,
    const unsigned* __restrict__ segkey, unsigned* __restrict__ valkey,
    unsigned* __restrict__ histA, int N, int M)
{
  __shared__ unsigned lh[BATCH * 256];
  for (int b = threadIdx.x; b < BATCH * 256; b += 256) lh[b] = 0;
  __syncthreads();
  const int stride = gridDim.x * 256;
  for (int i = blockIdx.x * 256 + threadIdx.x; i < N; i += stride) {
    unsigned kk = f2key(pred[i]);
    unsigned vk = (kk == segkey[vox[i]]) ? 0xFFFFFFFFu : kk;
    valkey[i] = vk;
    atomicAdd(&lh[(i / M) * 256 + (vk >> 24)], 1u);
  }
  __syncthreads();
  for (int b = threadIdx.x; b < BATCH * 256; b += 256)
    if (lh[b]) atomicAdd(&histA[b], lh[b]);
}

// Pass B: byte2 among elements whose byte1 matches the selected bin.
__global__ __launch_bounds__(256) void k_histB(
    const unsigned* __restrict__ valkey, const unsigned* __restrict__ sel,
    unsigned* __restrict__ histB, int N, int M)
{
  __shared__ unsigned lh[BATCH * 256];
  for (int b = threadIdx.x; b < BATCH * 256; b += 256) lh[b] = 0;
  __syncthreads();
  const int stride = gridDim.x * 256;
  for (int i = blockIdx.x * 256 + threadIdx.x; i < N; i += stride) {
    unsigned vk = valkey[i];
    int row = i / M;
    if ((vk >> 24) == sel[row * 4 + 0])
      atomicAdd(&lh[row * 256 + ((vk >> 16) & 255u)], 1u);
  }
  __syncthreads();
  for (int b = threadIdx.x; b < BATCH * 256; b += 256)
    if (lh[b]) atomicAdd(&histB[b], lh[b]);
}

// Pass C: low 16 bits among elements whose top16 matches (few -> global ok).
__global__ __launch_bounds__(256) void k_histC(
    const unsigned* __restrict__ valkey, const unsigned* __restrict__ sel,
    unsigned* __restrict__ histC, int N, int M)
{
  const int stride = gridDim.x * 256;
  for (int i = blockIdx.x * 256 + threadIdx.x; i < N; i += stride) {
    unsigned vk = valkey[i];
    int row = i / M;
    if ((vk >> 16) == sel[row * 4 + 0])
      atomicAdd(&histC[(size_t)row * 65536 + (vk & 0xFFFFu)], 1u);
  }
}

// scans: find smallest bin with cumulative count >= k (k = M - target_num)
__global__ void k_scan256(const unsigned* __restrict__ hist,
                          unsigned* __restrict__ sel,
                          const int* __restrict__ tnum, int M, int pass)
{
  const int row = blockIdx.x;
  __shared__ unsigned h[256];
  h[threadIdx.x] = hist[row * 256 + threadIdx.x];
  __syncthreads();
  if (threadIdx.x == 0) {
    const unsigned k = (unsigned)(M - tnum[0]);
    unsigned cum = (pass == 0) ? 0u : sel[row * 4 + 1];
    unsigned bin = 255;
    for (int i = 0; i < 256; ++i) {
      if (cum + h[i] >= k) { bin = (unsigned)i; break; }
      cum += h[i];
    }
    if (pass == 0) { sel[row * 4 + 0] = bin; }
    else           { sel[row * 4 + 0] = (sel[row * 4 + 0] << 8) | bin; }
    sel[row * 4 + 1] = cum;
  }
}

__global__ void k_scan64k(const unsigned* __restrict__ hist,
                          unsigned* __restrict__ sel,
                          const int* __restrict__ tnum, int M)
{
  const int row = blockIdx.x;
  const int t = threadIdx.x;  // 256
  const unsigned* h = hist + (size_t)row * 65536;
  __shared__ unsigned part[256];
  const uint4* hv = (const uint4*)(h + t * 256);
  unsigned s = 0;
  for (int i = 0; i < 64; ++i) { uint4 v = hv[i]; s += v.x + v.y + v.z + v.w; }
  part[t] = s;
  __syncthreads();
  if (t == 0) {
    const unsigned k = (unsigned)(M - tnum[0]);
    unsigned cum = sel[row * 4 + 1];
    int seg = 255;
    for (int i = 0; i < 256; ++i) {
      if (cum + part[i] >= k) { seg = i; break; }
      cum += part[i];
    }
    unsigned bin = 0;
    for (int i = 0; i < 256; ++i) {
      unsigned c = h[seg * 256 + i];
      if (cum + c >= k) { bin = (unsigned)(seg * 256 + i); break; }
      cum += c;
    }
    sel[row * 4 + 2] = (sel[row * 4 + 0] << 16) | bin;
  }
}

__global__ void k_scatter(const int* __restrict__ tidx, float* __restrict__ kt, int n)
{
  int i = blockIdx.x * blockDim.x + threadIdx.x;
  if (i < n) kt[tidx[i]] = 1.0f;
}

// zero rows that are not kept.  keep = (valkey > thr) | is_target
__global__ __launch_bounds__(256) void k_final(const unsigned* __restrict__ valkey,
    const float* __restrict__ kt, const unsigned* __restrict__ sel,
    float* __restrict__ out, int N, int M)
{
  const int wid = threadIdx.x >> 6;
  const int lane = threadIdx.x & 63;
  const int nw = gridDim.x * 4;
  for (int r = blockIdx.x * 4 + wid; r < N; r += nw) {
    unsigned vk = valkey[r];
    float kv = kt[r];
    unsigned thr = sel[(r / M) * 4 + 2];
    bool keep = (vk > thr) || (kv != 0.0f);
    if (!keep)
      *(float2*)&out[(size_t)r * C + lane * 2] = make_float2(0.f, 0.f);
  }
}

// ---------------------------------------------------------------------------
extern "C" void kernel_launch(void* const* d_in, const int* in_sizes, int n_in,
                              void* d_out, int out_size, void* d_ws, size_t ws_size,
                              hipStream_t stream)
{
  const float* fea = (const float*)d_in[0];
  const float* W1  = (const float*)d_in[1];
  const float* b1  = (const float*)d_in[2];
  const float* W2  = (const float*)d_in[3];
  const float* b2  = (const float*)d_in[4];
  const int* vox   = (const int*)d_in[5];
  const int* tidx  = (const int*)d_in[6];
  const int* tnum  = (const int*)d_in[7];

  const int N = in_sizes[5];      // 800000
  const int M = N / BATCH;        // 100000
  const int nT = in_sizes[6];     // 400000

  float* out  = (float*)d_out;
  float* pred = out + (size_t)N * C;
  float* kt   = pred + N;

  // workspace layout (zeroed region first, then valkey)
  char* w = (char*)d_ws;
  unsigned* segkey = (unsigned*)(w);                       // 512KB
  unsigned* histA  = (unsigned*)(w + (512u << 10));        // 8KB
  unsigned* histB  = (unsigned*)(w + (520u << 10));        // 8KB
  unsigned* sel    = (unsigned*)(w + (528u << 10));        // 4KB
  unsigned* histC  = (unsigned*)(w + (532u << 10));        // 2MB
  unsigned* valkey = (unsigned*)(w + (532u << 10) + (2u << 20));

  const size_t zbytes = (532u << 10) + (2u << 20);
  hipMemsetAsync(d_ws, 0, zbytes, stream);
  hipMemsetAsync(kt, 0, (size_t)N * sizeof(float), stream);

  k_scatter<<<(nT + 255) / 256, 256, 0, stream>>>(tidx, kt, nT);
  k_gemm<<<GEMM_BLOCKS, TPB, 0, stream>>>(fea, W1, b1, W2, b2, vox,
                                          out, pred, segkey, N);
  k_histA<<<HGRID, 256, 0, stream>>>(pred, vox, segkey, valkey, histA, N, M);
  k_scan256<<<BATCH, 256, 0, stream>>>(histA, sel, tnum, M, 0);
  k_histB<<<HGRID, 256, 0, stream>>>(valkey, sel, histB, N, M);
  k_scan256<<<BATCH, 256, 0, stream>>>(histB, sel, tnum, M, 1);
  k_histC<<<HGRID, 256, 0, stream>>>(valkey, sel, histC, N, M);
  k_scan64k<<<BATCH, 256, 0, stream>>>(histC, sel, tnum, M);
  k_final<<<2048, 256, 0, stream>>>(valkey, kt, sel, out, N, M);
}